// Round 11
// baseline (450.748 us; speedup 1.0000x reference)
//
#include <hip/hip_runtime.h>
#include <hip/hip_fp16.h>

typedef _Float16 f16x8 __attribute__((ext_vector_type(8)));
typedef _Float16 f16x4 __attribute__((ext_vector_type(4)));
typedef float f32x4 __attribute__((ext_vector_type(4)));

// Problem: B=2, L=2048, C=R=64. heads h = b*16 + mc*4 + mr (32 total),
// feature f = hc*16 + hr (256). Workspace (f16):
//   Q [32][2048][256], K [32][2048][256], Vt [32][256][2048], O/V [32][2048][256]

__device__ __forceinline__ void stage16(const _Float16* g, _Float16* l) {
  __builtin_amdgcn_global_load_lds(
      (const __attribute__((address_space(1))) void*)g,
      (__attribute__((address_space(3))) void*)l, 16, 0, 0);
}

__device__ __forceinline__ unsigned int pk2(float a, float b) {
  union { _Float16 h[2]; unsigned int u; } x;
  x.h[0] = (_Float16)a; x.h[1] = (_Float16)b;
  return x.u;
}

// split-f16: v = hi + lo with hi=(f16)v, lo=(f16)(v-hi). hi*hi+hi*lo+lo*hi in
// fp32 MFMA accum reconstructs the product to ~2^-22 relative (~fp32). Plain
// f16 inputs FAILED here (absmax 1536->7040): scores huge, so Q/K relative
// error is amplified through near-one-hot softmax argmax flips.
struct hl16 { _Float16 h, l; };
__device__ __forceinline__ hl16 split_f16(float v) {
  hl16 r;
  r.h = (_Float16)v;
  r.l = (_Float16)(v - (float)r.h);
  return r;
}

// ---------------- Kernel A: QKV bilinear projection, split-f16 MFMA -------------
__global__ __launch_bounds__(256) void qkv_kernel(
    const float* __restrict__ x, const float* __restrict__ u,
    const float* __restrict__ v, _Float16* __restrict__ Q,
    _Float16* __restrict__ K, _Float16* __restrict__ V) {
  __shared__ _Float16 sm[24576];     // 48 KB peak
  _Float16* xs_hi = sm;              // [d=64][n=64] swz
  _Float16* xs_lo = sm + 4096;
  _Float16* us_hi = sm + 8192;       // [m=64][n=64] swz
  _Float16* us_lo = sm + 12288;
  _Float16* Ts_hi = sm + 16384;      // [m=64][d=64] swz
  _Float16* Ts_lo = sm + 20480;
  _Float16* vc_hi = sm;              // chunk: [k=192][dd=32 pad 40]
  _Float16* vc_lo = sm + 7680;
  _Float16* qk16 = sm;               // [64][192] linear, final phase
  const int bl = blockIdx.x;
  const int b = bl >> 11, l = bl & 2047;
  const int t = threadIdx.x;
  const int w = t >> 6, lane = t & 63;
  const int l15 = lane & 15, quad = lane >> 4;

  // ---- stage x,u as hi/lo f16 planes, transposed + swizzled ----
  {
    const int d = t & 63, wq = t >> 6;
#pragma unroll
    for (int rr = 0; rr < 2; ++rr) {
      const int n0 = wq * 8 + rr * 32;
      f16x8 xh, xl, uh, ul;
#pragma unroll
      for (int j = 0; j < 8; ++j) {
        hl16 sx = split_f16(x[((size_t)bl << 12) + (n0 + j) * 64 + d]);
        hl16 su = split_f16(u[(n0 + j) * 64 + d]);
        xh[j] = sx.h; xl[j] = sx.l;
        uh[j] = su.h; ul[j] = su.l;
      }
      const int un = ((n0 >> 3) ^ (d & 7)) << 3;
      *(f16x8*)(xs_hi + (d << 6) + un) = xh;
      *(f16x8*)(xs_lo + (d << 6) + un) = xl;
      *(f16x8*)(us_hi + (d << 6) + un) = uh;
      *(f16x8*)(us_lo + (d << 6) + un) = ul;
    }
  }
  __syncthreads();

  // ---- gemm1: T[m][d] = sum_n u[n][m] x[n][d]; wave w owns d [w*16, w*16+16)
  {
    f32x4 dacc[4];
#pragma unroll
    for (int mt = 0; mt < 4; ++mt) dacc[mt] = (f32x4){0.f, 0.f, 0.f, 0.f};
    const int d = (w << 4) | l15;
#pragma unroll
    for (int ks = 0; ks < 2; ++ks) {
      const int ug = (((ks * 4 + quad) ^ (d & 7)) << 3);
      f16x8 bh = *(const f16x8*)(xs_hi + (d << 6) + ug);
      f16x8 blo = *(const f16x8*)(xs_lo + (d << 6) + ug);
#pragma unroll
      for (int mt = 0; mt < 4; ++mt) {
        const int m = (mt << 4) | l15;
        const int um = (((ks * 4 + quad) ^ (m & 7)) << 3);
        f16x8 ah = *(const f16x8*)(us_hi + (m << 6) + um);
        f16x8 al = *(const f16x8*)(us_lo + (m << 6) + um);
        dacc[mt] = __builtin_amdgcn_mfma_f32_16x16x32_f16(ah, bh, dacc[mt], 0, 0, 0);
        dacc[mt] = __builtin_amdgcn_mfma_f32_16x16x32_f16(ah, blo, dacc[mt], 0, 0, 0);
        dacc[mt] = __builtin_amdgcn_mfma_f32_16x16x32_f16(al, bh, dacc[mt], 0, 0, 0);
      }
    }
    // Ts hi/lo write (scalar): D row = (mt<<4)+quad*4+r, col d=(w<<4)|l15
#pragma unroll
    for (int mt = 0; mt < 4; ++mt) {
#pragma unroll
      for (int r = 0; r < 4; ++r) {
        const int m = (mt << 4) | (quad << 2) | r;
        const int dd = (w << 4) | l15;
        const int off = (m << 6) + ((((dd >> 3) ^ (m & 7)) << 3) | (dd & 7));
        hl16 st = split_f16(dacc[mt][r]);
        Ts_hi[off] = st.h;
        Ts_lo[off] = st.l;
      }
    }
  }
  __syncthreads();

  // ---- gemm2: Y[m][k] = sum_d T[m][d] v[d][k]; wave w owns k [w*48, w*48+48)
  f32x4 cacc[4][3];
#pragma unroll
  for (int mt = 0; mt < 4; ++mt)
#pragma unroll
    for (int kt = 0; kt < 3; ++kt) cacc[mt][kt] = (f32x4){0.f, 0.f, 0.f, 0.f};

  for (int chk = 0; chk < 2; ++chk) {
    // stage v chunk (d in [chk*32, chk*32+32)) as hi/lo, rows padded to 40
#pragma unroll
    for (int rr = 0; rr < 3; ++rr) {
      const int c768 = t + 256 * rr;
      const int k = c768 >> 2, sg = c768 & 3;
      f16x8 vh, vl;
#pragma unroll
      for (int j = 0; j < 8; ++j) {
        hl16 sv = split_f16(v[(chk * 32 + sg * 8 + j) * 192 + k]);
        vh[j] = sv.h; vl[j] = sv.l;
      }
      *(f16x8*)(vc_hi + k * 40 + sg * 8) = vh;
      *(f16x8*)(vc_lo + k * 40 + sg * 8) = vl;
    }
    __syncthreads();
    // A-frags for this chunk's d-slice from Ts
    f16x8 ah[4], al[4];
#pragma unroll
    for (int mt = 0; mt < 4; ++mt) {
      const int m = (mt << 4) | l15;
      const int off = (m << 6) + (((chk * 4 + quad) ^ (m & 7)) << 3);
      ah[mt] = *(const f16x8*)(Ts_hi + off);
      al[mt] = *(const f16x8*)(Ts_lo + off);
    }
#pragma unroll
    for (int kt = 0; kt < 3; ++kt) {
      const int k = w * 48 + kt * 16 + l15;
      f16x8 bh = *(const f16x8*)(vc_hi + k * 40 + quad * 8);
      f16x8 blo = *(const f16x8*)(vc_lo + k * 40 + quad * 8);
#pragma unroll
      for (int mt = 0; mt < 4; ++mt) {
        cacc[mt][kt] = __builtin_amdgcn_mfma_f32_16x16x32_f16(ah[mt], bh, cacc[mt][kt], 0, 0, 0);
        cacc[mt][kt] = __builtin_amdgcn_mfma_f32_16x16x32_f16(ah[mt], blo, cacc[mt][kt], 0, 0, 0);
        cacc[mt][kt] = __builtin_amdgcn_mfma_f32_16x16x32_f16(al[mt], bh, cacc[mt][kt], 0, 0, 0);
      }
    }
    __syncthreads();  // chunk region free for restage / qk16
  }

  // ---- f16 qkv into LDS [64][192]
#pragma unroll
  for (int mt = 0; mt < 4; ++mt)
#pragma unroll
    for (int kt = 0; kt < 3; ++kt) {
      const int k = w * 48 + kt * 16 + l15;
#pragma unroll
      for (int r = 0; r < 4; ++r) {
        const int m = (mt << 4) | (quad << 2) | r;
        qk16[m * 192 + k] = (_Float16)cacc[mt][kt][r];
      }
    }
  __syncthreads();

  // gather + coalesced 32B stores: run rho = m*12 + k64*4 + mr -> 16 consecutive f
#pragma unroll
  for (int s = 0; s < 3; ++s) {
    const int rho = t + 256 * s;
    const int m = rho / 12, rem = rho - m * 12;
    const int k64 = rem >> 2, mr = rem & 3;
    const int chf = 3 * m + k64;          // t3*64 + ch
    const int t3 = chf >> 6, ch = chf & 63;
    const int f0 = (ch & 15) << 4;
    const int h = (b << 4) | ((ch >> 4) << 2) | mr;
    const _Float16* src = qk16 + m * 192 + k64 * 64 + mr * 16;
    f16x8 a0 = *(const f16x8*)src;
    f16x8 a1 = *(const f16x8*)(src + 8);
    _Float16* base = (t3 == 0) ? Q : (t3 == 1) ? K : V;
    _Float16* dst = base + (((size_t)h * 2048 + l) << 8) + f0;
    *(f16x8*)dst = a0;
    *(f16x8*)(dst + 8) = a1;
  }
}

// ---------------- Kernel A2: V [h][l][f] -> Vt [h][f][l] (64x64 LDS tiles) ------
__global__ __launch_bounds__(256) void vtrans_kernel(
    const _Float16* __restrict__ V, _Float16* __restrict__ Vt) {
  __shared__ _Float16 tb[64 * 72];
  const int bid = blockIdx.x;
  const int h = bid >> 7;
  const int lt = (bid >> 2) & 31;
  const int ft = bid & 3;
  const int l0 = lt << 6, f0 = ft << 6;
  const int t = threadIdx.x;
  const int r = t >> 2, s = (t & 3) << 4;
  const _Float16* src = V + (((size_t)h * 2048 + l0 + r) << 8) + f0 + s;
  *(f16x8*)(tb + r * 72 + s) = *(const f16x8*)src;
  *(f16x8*)(tb + r * 72 + s + 8) = *(const f16x8*)(src + 8);
  __syncthreads();
  _Float16 buf[16];
#pragma unroll
  for (int j = 0; j < 16; ++j) buf[j] = tb[(s + j) * 72 + r];
  _Float16* dst = Vt + (((size_t)(h << 8) + f0 + r) << 11) + l0 + s;
  *(f16x8*)dst = *(f16x8*)buf;
  *(f16x8*)(dst + 8) = *(f16x8*)(buf + 8);
}

// ---------------- Kernel B: flash attention, S^T dataflow, MFMA 16x16x32 --------
// R8 structure at (256,2): 512 blocks x 4 waves, wave = 32 queries (2 qh; Ks
// reads amortize over both -> R7-level LDS traffic). LDS 48KB (Ks dbuf + Vs
// single + no Ps) -> 3 blocks/CU = 12 waves/CU. R8's (256,3) capped VGPR at 84
// and spilled oacc (WRITE 42->752MB); (256,2) allows ~128 VGPR, no spill.
// Schedule: top: stage_K(kt+1); vmcnt(4) [drains V(kt)+K(kt), leaves K(kt+1)];
// barrier; QK; softmax+shfl P-exch; PV(Vs); barrier; stage_V(kt+1).
__global__ __launch_bounds__(256, 2) void attn_kernel(
    const _Float16* __restrict__ Q, const _Float16* __restrict__ K,
    const _Float16* __restrict__ Vt, _Float16* __restrict__ O) {
  __shared__ _Float16 Ks[2][32 * 256];     // swizzled: mem[row][u]=K[row][u^(row&7)]
  __shared__ _Float16 Vs[256 * 32];        // 16B slots XOR-swizzled: i' = i ^ (g&7)
  const int i = blockIdx.x;
  const int h = (i & 7) * 4 + (i >> 7);    // XCD-aware: 4 heads per XCD
  const int qt = (i >> 3) & 15;
  const int tid = threadIdx.x;
  const int w = tid >> 6, lane = tid & 63;
  const int l15 = lane & 15, quad = lane >> 4;
  const int q0 = qt * 128 + w * 32;

  const _Float16* Kt = K + (((size_t)h * 2048) << 8);
  const _Float16* Vtb = Vt + (((size_t)h << 8) << 11);

  // Q fragments as B-operand (n=query=l15, k=feat=kc*32+quad*8+j)
  f16x8 qf[2][8];
#pragma unroll
  for (int qh = 0; qh < 2; ++qh) {
    const _Float16* qb = Q + (((size_t)h * 2048 + q0 + qh * 16 + l15) << 8) + quad * 8;
#pragma unroll
    for (int kc = 0; kc < 8; ++kc) qf[qh][kc] = *(const f16x8*)(qb + kc * 32);
  }

  // O^T accumulators: oacc[qh][fb][r] = O^T[feat=fb*16+quad*4+r][query=qh*16+l15]
  f32x4 oacc[2][16];
#pragma unroll
  for (int qh = 0; qh < 2; ++qh)
#pragma unroll
    for (int fb = 0; fb < 16; ++fb) oacc[qh][fb] = (f32x4){0.f, 0.f, 0.f, 0.f};
  float m2[2] = {-1e30f, -1e30f};  // running max per query (base-2 units)
  float ell[2] = {0.f, 0.f};      // lane-partial (this quad's keys)
  const float SC = 23.083120654223414f;  // 16 * log2(e)

  auto stage_K = [&](int kt, int bb) {
    const int k0 = kt * 32;
#pragma unroll
    for (int o = 0; o < 4; ++o) {
      const int c = tid + o * 256;
      const int row = c >> 5, unit = c & 31;
      stage16(Kt + (((size_t)(k0 + row)) << 8) + ((unit ^ (row & 7)) << 3),
              &Ks[bb][c * 8]);
    }
  };
  auto stage_V = [&](int kt) {
    const int k0 = kt * 32;
#pragma unroll
    for (int o = 0; o < 4; ++o) {
      const int c = tid + o * 256;
      // physical 16B slot c; logical slot sl = (g<<3)|(ip^(g&7)) (involution)
      const int g = c >> 3, ip = c & 7;
      const int sl = (g << 3) | (ip ^ (g & 7));
      const int f = sl >> 2, ku = sl & 3;
      stage16(Vtb + (((size_t)f) << 11) + k0 + ku * 8, &Vs[c * 8]);
    }
  };

  stage_K(0, 0);
  stage_V(0);
  for (int kt = 0; kt < 64; ++kt) {
    const int cb = kt & 1;
    if (kt < 63) {
      stage_K(kt + 1, cb ^ 1);
      asm volatile("s_waitcnt vmcnt(4)" ::: "memory");
    } else {
      asm volatile("s_waitcnt vmcnt(0)" ::: "memory");
    }
    __builtin_amdgcn_s_barrier();
    asm volatile("" ::: "memory");

    // S^T = K Q^T : c[kh][qh]; D[m=key=quad*4+r][n=query=l15]
    f32x4 c00 = {0.f, 0.f, 0.f, 0.f}, c01 = c00, c10 = c00, c11 = c00;
#pragma unroll
    for (int kc = 0; kc < 8; ++kc) {
      const int u0 = ((kc * 4 + quad) ^ (l15 & 7)) << 3;
      f16x8 kf0 = *(const f16x8*)(&Ks[cb][l15 * 256 + u0]);
      f16x8 kf1 = *(const f16x8*)(&Ks[cb][(16 + l15) * 256 + u0]);
      c00 = __builtin_amdgcn_mfma_f32_16x16x32_f16(kf0, qf[0][kc], c00, 0, 0, 0);
      c01 = __builtin_amdgcn_mfma_f32_16x16x32_f16(kf0, qf[1][kc], c01, 0, 0, 0);
      c10 = __builtin_amdgcn_mfma_f32_16x16x32_f16(kf1, qf[0][kc], c10, 0, 0, 0);
      c11 = __builtin_amdgcn_mfma_f32_16x16x32_f16(kf1, qf[1][kc], c11, 0, 0, 0);
    }

    // online softmax: in-lane 8-max + xor16/xor32; defer-max threshold 8 (T13)
    float alpha[2];
    unsigned int pA0[2], pA1[2], pB0[2], pB1[2];  // pk2'd P^T quarters (kh0/kh1)
    bool upd = false;
#pragma unroll
    for (int qh = 0; qh < 2; ++qh) {
      const f32x4 ck0 = qh ? c01 : c00;
      const f32x4 ck1 = qh ? c11 : c10;
      float s0[4], s1[4];
#pragma unroll
      for (int r = 0; r < 4; ++r) { s0[r] = ck0[r] * SC; s1[r] = ck1[r] * SC; }
      float mx = fmaxf(fmaxf(fmaxf(s0[0], s0[1]), fmaxf(s0[2], s0[3])),
                       fmaxf(fmaxf(s1[0], s1[1]), fmaxf(s1[2], s1[3])));
      mx = fmaxf(mx, __shfl_xor(mx, 16));
      mx = fmaxf(mx, __shfl_xor(mx, 32));
      const float mo = m2[qh];
      const bool u8 = (mx > mo + 8.f);   // defer-max: P bounded by 2^8
      const float mn = u8 ? mx : mo;
      m2[qh] = mn;
      upd |= u8;
      const float a = exp2f(mo - mn);
      alpha[qh] = a;
      float p0[4], p1[4];
#pragma unroll
      for (int r = 0; r < 4; ++r) { p0[r] = exp2f(s0[r] - mn); p1[r] = exp2f(s1[r] - mn); }
      ell[qh] = ell[qh] * a + ((p0[0] + p0[1]) + (p0[2] + p0[3])) +
                ((p1[0] + p1[1]) + (p1[2] + p1[3]));
      pA0[qh] = pk2(p0[0], p0[1]);
      pA1[qh] = pk2(p0[2], p0[3]);
      pB0[qh] = pk2(p1[0], p1[1]);
      pB1[qh] = pk2(p1[2], p1[3]);
    }
    if (__any(upd)) {
#pragma unroll
      for (int qh = 0; qh < 2; ++qh)
#pragma unroll
        for (int fb = 0; fb < 16; ++fb) oacc[qh][fb] *= alpha[qh];
    }
    // P^T exchange intra-wave: target (quad,l15) needs row dwords 4*quad..4*quad+3
    // = {A0,A1}(srcLo,srcHi) for quad<2, {B0,B1}(srcLo,srcHi) for quad>=2,
    // srcLo = quad 2*(quad&1), srcHi = srcLo+1 (same l15).
    f16x8 pf[2];
    {
      const int srcLo = ((quad & 1) << 5) | l15;
      const int srcHi = srcLo + 16;
      const bool hi = (quad >> 1) != 0;
#pragma unroll
      for (int qh = 0; qh < 2; ++qh) {
        unsigned int a0 = __shfl(pA0[qh], srcLo), b0 = __shfl(pB0[qh], srcLo);
        unsigned int a1 = __shfl(pA1[qh], srcLo), b1 = __shfl(pB1[qh], srcLo);
        unsigned int a2 = __shfl(pA0[qh], srcHi), b2 = __shfl(pB0[qh], srcHi);
        unsigned int a3 = __shfl(pA1[qh], srcHi), b3 = __shfl(pB1[qh], srcHi);
        union { f16x8 v; unsigned int d[4]; } tp;
        tp.d[0] = hi ? b0 : a0;
        tp.d[1] = hi ? b1 : a1;
        tp.d[2] = hi ? b2 : a2;
        tp.d[3] = hi ? b3 : a3;
        pf[qh] = tp.v;
      }
    }
    // O^T += V^T P^T (vf shared across qh); Vs read via slot swizzle (conflict-free)
#pragma unroll
    for (int fb = 0; fb < 16; ++fb) {
      const int f = fb * 16 + l15;
      const int g = f >> 1;
      const int ip = (((f & 1) << 2) | quad) ^ (g & 7);
      f16x8 vf = *(const f16x8*)(&Vs[(((g << 3) | ip)) * 8]);
      oacc[0][fb] = __builtin_amdgcn_mfma_f32_16x16x32_f16(vf, pf[0], oacc[0][fb], 0, 0, 0);
      oacc[1][fb] = __builtin_amdgcn_mfma_f32_16x16x32_f16(vf, pf[1], oacc[1][fb], 0, 0, 0);
    }
    asm volatile("" ::: "memory");
    __builtin_amdgcn_s_barrier();
    asm volatile("" ::: "memory");
    if (kt < 63) stage_V(kt + 1);  // all PV reads of Vs done (barrier above)
  }

  // epilogue: reduce lane-partial ell over quads, write O[h][query][feat]
#pragma unroll
  for (int qh = 0; qh < 2; ++qh) {
    float e = ell[qh];
    e += __shfl_xor(e, 16);
    e += __shfl_xor(e, 32);
    const float inv = 1.f / e;
    _Float16* ob = O + (((size_t)h * 2048 + q0 + qh * 16 + l15) << 8) + quad * 4;
#pragma unroll
    for (int fb = 0; fb < 16; ++fb) {
      f16x4 ov;
#pragma unroll
      for (int r = 0; r < 4; ++r) ov[r] = (_Float16)(oacc[qh][fb][r] * inv);
      *(f16x4*)(ob + fb * 16) = ov;
    }
  }
}

// ---------------- Kernel C: gather + output bilinear via split-f16 MFMA ---------
// Reassociated: out = pu^T (os pv). gemm1: G[n][k] = sum_d os[n][d] pv[d][k]
// (os is exact f16 from O -> 2-term split). gemm2: out[m][k] = sum_n pu[n][m]
// G[n][k] (pu, G split -> 3-term). LDS 40KB (G planes reuse os/pvt regions).
__global__ __launch_bounds__(256) void proj_kernel(
    const _Float16* __restrict__ O, const float* __restrict__ pu,
    const float* __restrict__ pv, float* __restrict__ out) {
  __shared__ _Float16 sm[20480];   // 40 KB
  _Float16* os = sm;               // [n=64][d=64] swz (f16 exact)
  _Float16* put_hi = sm + 4096;    // [m=64][n=64] swz
  _Float16* put_lo = sm + 8192;
  _Float16* pvt_hi = sm + 12288;   // [k=64][d=64] swz
  _Float16* pvt_lo = sm + 16384;
  _Float16* gt_hi = sm;            // [k=64][n=64] swz, reuses os region
  _Float16* gt_lo = sm + 12288;    // reuses pvt_hi region
  const int bl = blockIdx.x;
  const int b = bl >> 11, l = bl & 2047;
  const int t = threadIdx.x;
  const int w = t >> 6, lane = t & 63;
  const int l15 = lane & 15, quad = lane >> 4;

  {  // gather this (b,l)'s 64x64 attention output -> os[n][d] f16 swizzled
    const int hh = t >> 4, hc = t & 15;
    const int mc = hh >> 2, mr = hh & 3;
    const int hg = (b << 4) | hh;
    const _Float16* src = O + (((size_t)hg * 2048 + l) << 8) + hc * 16;
    const int n = mc * 16 + hc, d0 = mr * 16;
    f16x8 v0 = *(const f16x8*)(src);
    f16x8 v1 = *(const f16x8*)(src + 8);
    *(f16x8*)(os + (n << 6) + ((((d0 >> 3) + 0) ^ (n & 7)) << 3)) = v0;
    *(f16x8*)(os + (n << 6) + ((((d0 >> 3) + 1) ^ (n & 7)) << 3)) = v1;
  }
  {  // stage pu -> put[m][n] hi/lo; pv -> pvt[k][d] hi/lo (strided scalar, L2-hot)
    const int c = t & 63, wq = t >> 6;
#pragma unroll
    for (int rr = 0; rr < 2; ++rr) {
      const int r0 = wq * 8 + rr * 32;
      f16x8 uh, ul, vh, vl;
#pragma unroll
      for (int j = 0; j < 8; ++j) {
        hl16 su = split_f16(pu[(r0 + j) * 64 + c]);
        hl16 sv = split_f16(pv[(r0 + j) * 64 + c]);
        uh[j] = su.h; ul[j] = su.l;
        vh[j] = sv.h; vl[j] = sv.l;
      }
      const int un = ((r0 >> 3) ^ (c & 7)) << 3;
      *(f16x8*)(put_hi + (c << 6) + un) = uh;
      *(f16x8*)(put_lo + (c << 6) + un) = ul;
      *(f16x8*)(pvt_hi + (c << 6) + un) = vh;
      *(f16x8*)(pvt_lo + (c << 6) + un) = vl;
    }
  }
  __syncthreads();

  // gemm1: G[n][k] = sum_d os[n][d] pv[d][k]; wave w owns k in [w*16, w*16+16)
  f32x4 gacc[4];
#pragma unroll
  for (int nt = 0; nt < 4; ++nt) gacc[nt] = (f32x4){0.f, 0.f, 0.f, 0.f};
  {
    const int k = (w << 4) | l15;
#pragma unroll
    for (int ks = 0; ks < 2; ++ks) {
      const int uk = (((ks * 4 + quad) ^ (k & 7)) << 3);
      f16x8 bh = *(const f16x8*)(pvt_hi + (k << 6) + uk);
      f16x8 blo = *(const f16x8*)(pvt_lo + (k << 6) + uk);
#pragma unroll
      for (int nt = 0; nt < 4; ++nt) {
        const int n = (nt << 4) | l15;
        const int un = (((ks * 4 + quad) ^ (n & 7)) << 3);
        f16x8 a = *(const f16x8*)(os + (n << 6) + un);
        gacc[nt] = __builtin_amdgcn_mfma_f32_16x16x32_f16(a, bh, gacc[nt], 0, 0, 0);
        gacc[nt] = __builtin_amdgcn_mfma_f32_16x16x32_f16(a, blo, gacc[nt], 0, 0, 0);
      }
    }
  }
  __syncthreads();  // all waves done reading os/pvt before G overwrites them
  {
    const int k = (w << 4) | l15;
#pragma unroll
    for (int nt = 0; nt < 4; ++nt) {
#pragma unroll
      for (int r = 0; r < 4; ++r) {
        const int n = (nt << 4) | (quad << 2) | r;
        const int off = (k << 6) + ((((n >> 3) ^ (k & 7)) << 3) | (n & 7));
        hl16 sg = split_f16(gacc[nt][r]);
        gt_hi[off] = sg.h;
        gt_lo[off] = sg.l;
      }
    }
  }
  __syncthreads();

  // gemm2: out[m][k] = sum_n pu[n][m] G[n][k]; wave w owns k in [w*16, w*16+16)
  {
    f32x4 cacc[4];
#pragma unroll
    for (int mt = 0; mt < 4; ++mt) cacc[mt] = (f32x4){0.f, 0.f, 0.f, 0.f};
    const int k = (w << 4) | l15;
#pragma unroll
    for (int ks = 0; ks < 2; ++ks) {
      const int uk = (((ks * 4 + quad) ^ (k & 7)) << 3);
      f16x8 bh = *(const f16x8*)(gt_hi + (k << 6) + uk);
      f16x8 blo = *(const f16x8*)(gt_lo + (k << 6) + uk);
#pragma unroll
      for (int mt = 0; mt < 4; ++mt) {
        const int m = (mt << 4) | l15;
        const int um = (((ks * 4 + quad) ^ (m & 7)) << 3);
        f16x8 ah = *(const f16x8*)(put_hi + (m << 6) + um);
        f16x8 al = *(const f16x8*)(put_lo + (m << 6) + um);
        cacc[mt] = __builtin_amdgcn_mfma_f32_16x16x32_f16(ah, bh, cacc[mt], 0, 0, 0);
        cacc[mt] = __builtin_amdgcn_mfma_f32_16x16x32_f16(ah, blo, cacc[mt], 0, 0, 0);
        cacc[mt] = __builtin_amdgcn_mfma_f32_16x16x32_f16(al, bh, cacc[mt], 0, 0, 0);
      }
    }
    float* og = out + ((size_t)bl << 12);
#pragma unroll
    for (int mt = 0; mt < 4; ++mt) {
#pragma unroll
      for (int r = 0; r < 4; ++r) {
        const int m = (mt << 4) | (quad << 2) | r;
        og[m * 64 + k] = cacc[mt][r];
      }
    }
  }
}

extern "C" void kernel_launch(void* const* d_in, const int* in_sizes, int n_in,
                              void* d_out, int out_size, void* d_ws, size_t ws_size,
                              hipStream_t stream) {
  (void)in_sizes; (void)n_in; (void)out_size; (void)ws_size;
  const float* x = (const float*)d_in[0];
  const float* u = (const float*)d_in[1];
  const float* v = (const float*)d_in[2];
  const float* pu = (const float*)d_in[3];
  const float* pv = (const float*)d_in[4];
  const size_t SEG = (size_t)32 * 2048 * 256;  // 16.7M f16 elements
  _Float16* Q = (_Float16*)d_ws;
  _Float16* K = Q + SEG;
  _Float16* Vt = K + SEG;
  _Float16* O = Vt + SEG;  // also V staging (consumed by vtrans before O writes)
  _Float16* V = O;
  qkv_kernel<<<4096, 256, 0, stream>>>(x, u, v, Q, K, V);
  vtrans_kernel<<<4096, 256, 0, stream>>>(V, Vt);
  attn_kernel<<<512, 256, 0, stream>>>(Q, K, Vt, O);
  proj_kernel<<<4096, 256, 0, stream>>>(O, pu, pv, (float*)d_out);
}

// Round 12
// 390.676 us; speedup vs baseline: 1.1538x; 1.1538x over previous
//
#include <hip/hip_runtime.h>
#include <hip/hip_fp16.h>

typedef _Float16 f16x8 __attribute__((ext_vector_type(8)));
typedef _Float16 f16x4 __attribute__((ext_vector_type(4)));
typedef float f32x4 __attribute__((ext_vector_type(4)));

// Problem: B=2, L=2048, C=R=64. heads h = b*16 + mc*4 + mr (32 total),
// feature f = hc*16 + hr (256). Workspace (f16):
//   Q [32][2048][256], K [32][2048][256], Vt [32][256][2048], O/V [32][2048][256]

__device__ __forceinline__ void stage16(const _Float16* g, _Float16* l) {
  __builtin_amdgcn_global_load_lds(
      (const __attribute__((address_space(1))) void*)g,
      (__attribute__((address_space(3))) void*)l, 16, 0, 0);
}

__device__ __forceinline__ unsigned int pk2(float a, float b) {
  union { _Float16 h[2]; unsigned int u; } x;
  x.h[0] = (_Float16)a; x.h[1] = (_Float16)b;
  return x.u;
}

// split-f16: v = hi + lo with hi=(f16)v, lo=(f16)(v-hi). hi*hi+hi*lo+lo*hi in
// fp32 MFMA accum reconstructs the product to ~2^-22 relative (~fp32). Plain
// f16 inputs FAILED here (absmax 1536->7040): scores huge, so Q/K relative
// error is amplified through near-one-hot softmax argmax flips.
struct hl16 { _Float16 h, l; };
__device__ __forceinline__ hl16 split_f16(float v) {
  hl16 r;
  r.h = (_Float16)v;
  r.l = (_Float16)(v - (float)r.h);
  return r;
}

// ---------------- Kernel A: QKV bilinear projection, split-f16 MFMA -------------
__global__ __launch_bounds__(256) void qkv_kernel(
    const float* __restrict__ x, const float* __restrict__ u,
    const float* __restrict__ v, _Float16* __restrict__ Q,
    _Float16* __restrict__ K, _Float16* __restrict__ V) {
  __shared__ _Float16 sm[24576];     // 48 KB peak
  _Float16* xs_hi = sm;              // [d=64][n=64] swz
  _Float16* xs_lo = sm + 4096;
  _Float16* us_hi = sm + 8192;       // [m=64][n=64] swz
  _Float16* us_lo = sm + 12288;
  _Float16* Ts_hi = sm + 16384;      // [m=64][d=64] swz
  _Float16* Ts_lo = sm + 20480;
  _Float16* vc_hi = sm;              // chunk: [k=192][dd=32 pad 40]
  _Float16* vc_lo = sm + 7680;
  _Float16* qk16 = sm;               // [64][192] linear, final phase
  const int bl = blockIdx.x;
  const int b = bl >> 11, l = bl & 2047;
  const int t = threadIdx.x;
  const int w = t >> 6, lane = t & 63;
  const int l15 = lane & 15, quad = lane >> 4;

  // ---- stage x,u as hi/lo f16 planes, transposed + swizzled ----
  {
    const int d = t & 63, wq = t >> 6;
#pragma unroll
    for (int rr = 0; rr < 2; ++rr) {
      const int n0 = wq * 8 + rr * 32;
      f16x8 xh, xl, uh, ul;
#pragma unroll
      for (int j = 0; j < 8; ++j) {
        hl16 sx = split_f16(x[((size_t)bl << 12) + (n0 + j) * 64 + d]);
        hl16 su = split_f16(u[(n0 + j) * 64 + d]);
        xh[j] = sx.h; xl[j] = sx.l;
        uh[j] = su.h; ul[j] = su.l;
      }
      const int un = ((n0 >> 3) ^ (d & 7)) << 3;
      *(f16x8*)(xs_hi + (d << 6) + un) = xh;
      *(f16x8*)(xs_lo + (d << 6) + un) = xl;
      *(f16x8*)(us_hi + (d << 6) + un) = uh;
      *(f16x8*)(us_lo + (d << 6) + un) = ul;
    }
  }
  __syncthreads();

  // ---- gemm1: T[m][d] = sum_n u[n][m] x[n][d]; wave w owns d [w*16, w*16+16)
  {
    f32x4 dacc[4];
#pragma unroll
    for (int mt = 0; mt < 4; ++mt) dacc[mt] = (f32x4){0.f, 0.f, 0.f, 0.f};
    const int d = (w << 4) | l15;
#pragma unroll
    for (int ks = 0; ks < 2; ++ks) {
      const int ug = (((ks * 4 + quad) ^ (d & 7)) << 3);
      f16x8 bh = *(const f16x8*)(xs_hi + (d << 6) + ug);
      f16x8 blo = *(const f16x8*)(xs_lo + (d << 6) + ug);
#pragma unroll
      for (int mt = 0; mt < 4; ++mt) {
        const int m = (mt << 4) | l15;
        const int um = (((ks * 4 + quad) ^ (m & 7)) << 3);
        f16x8 ah = *(const f16x8*)(us_hi + (m << 6) + um);
        f16x8 al = *(const f16x8*)(us_lo + (m << 6) + um);
        dacc[mt] = __builtin_amdgcn_mfma_f32_16x16x32_f16(ah, bh, dacc[mt], 0, 0, 0);
        dacc[mt] = __builtin_amdgcn_mfma_f32_16x16x32_f16(ah, blo, dacc[mt], 0, 0, 0);
        dacc[mt] = __builtin_amdgcn_mfma_f32_16x16x32_f16(al, bh, dacc[mt], 0, 0, 0);
      }
    }
    // Ts hi/lo write (scalar): D row = (mt<<4)+quad*4+r, col d=(w<<4)|l15
#pragma unroll
    for (int mt = 0; mt < 4; ++mt) {
#pragma unroll
      for (int r = 0; r < 4; ++r) {
        const int m = (mt << 4) | (quad << 2) | r;
        const int dd = (w << 4) | l15;
        const int off = (m << 6) + ((((dd >> 3) ^ (m & 7)) << 3) | (dd & 7));
        hl16 st = split_f16(dacc[mt][r]);
        Ts_hi[off] = st.h;
        Ts_lo[off] = st.l;
      }
    }
  }
  __syncthreads();

  // ---- gemm2: Y[m][k] = sum_d T[m][d] v[d][k]; wave w owns k [w*48, w*48+48)
  f32x4 cacc[4][3];
#pragma unroll
  for (int mt = 0; mt < 4; ++mt)
#pragma unroll
    for (int kt = 0; kt < 3; ++kt) cacc[mt][kt] = (f32x4){0.f, 0.f, 0.f, 0.f};

  for (int chk = 0; chk < 2; ++chk) {
    // stage v chunk (d in [chk*32, chk*32+32)) as hi/lo, rows padded to 40
#pragma unroll
    for (int rr = 0; rr < 3; ++rr) {
      const int c768 = t + 256 * rr;
      const int k = c768 >> 2, sg = c768 & 3;
      f16x8 vh, vl;
#pragma unroll
      for (int j = 0; j < 8; ++j) {
        hl16 sv = split_f16(v[(chk * 32 + sg * 8 + j) * 192 + k]);
        vh[j] = sv.h; vl[j] = sv.l;
      }
      *(f16x8*)(vc_hi + k * 40 + sg * 8) = vh;
      *(f16x8*)(vc_lo + k * 40 + sg * 8) = vl;
    }
    __syncthreads();
    // A-frags for this chunk's d-slice from Ts
    f16x8 ah[4], al[4];
#pragma unroll
    for (int mt = 0; mt < 4; ++mt) {
      const int m = (mt << 4) | l15;
      const int off = (m << 6) + (((chk * 4 + quad) ^ (m & 7)) << 3);
      ah[mt] = *(const f16x8*)(Ts_hi + off);
      al[mt] = *(const f16x8*)(Ts_lo + off);
    }
#pragma unroll
    for (int kt = 0; kt < 3; ++kt) {
      const int k = w * 48 + kt * 16 + l15;
      f16x8 bh = *(const f16x8*)(vc_hi + k * 40 + quad * 8);
      f16x8 blo = *(const f16x8*)(vc_lo + k * 40 + quad * 8);
#pragma unroll
      for (int mt = 0; mt < 4; ++mt) {
        cacc[mt][kt] = __builtin_amdgcn_mfma_f32_16x16x32_f16(ah[mt], bh, cacc[mt][kt], 0, 0, 0);
        cacc[mt][kt] = __builtin_amdgcn_mfma_f32_16x16x32_f16(ah[mt], blo, cacc[mt][kt], 0, 0, 0);
        cacc[mt][kt] = __builtin_amdgcn_mfma_f32_16x16x32_f16(al[mt], bh, cacc[mt][kt], 0, 0, 0);
      }
    }
    __syncthreads();  // chunk region free for restage / qk16
  }

  // ---- f16 qkv into LDS [64][192]
#pragma unroll
  for (int mt = 0; mt < 4; ++mt)
#pragma unroll
    for (int kt = 0; kt < 3; ++kt) {
      const int k = w * 48 + kt * 16 + l15;
#pragma unroll
      for (int r = 0; r < 4; ++r) {
        const int m = (mt << 4) | (quad << 2) | r;
        qk16[m * 192 + k] = (_Float16)cacc[mt][kt][r];
      }
    }
  __syncthreads();

  // gather + coalesced 32B stores: run rho = m*12 + k64*4 + mr -> 16 consecutive f
#pragma unroll
  for (int s = 0; s < 3; ++s) {
    const int rho = t + 256 * s;
    const int m = rho / 12, rem = rho - m * 12;
    const int k64 = rem >> 2, mr = rem & 3;
    const int chf = 3 * m + k64;          // t3*64 + ch
    const int t3 = chf >> 6, ch = chf & 63;
    const int f0 = (ch & 15) << 4;
    const int h = (b << 4) | ((ch >> 4) << 2) | mr;
    const _Float16* src = qk16 + m * 192 + k64 * 64 + mr * 16;
    f16x8 a0 = *(const f16x8*)src;
    f16x8 a1 = *(const f16x8*)(src + 8);
    _Float16* base = (t3 == 0) ? Q : (t3 == 1) ? K : V;
    _Float16* dst = base + (((size_t)h * 2048 + l) << 8) + f0;
    *(f16x8*)dst = a0;
    *(f16x8*)(dst + 8) = a1;
  }
}

// ---------------- Kernel A2: V [h][l][f] -> Vt [h][f][l] (64x64 LDS tiles) ------
__global__ __launch_bounds__(256) void vtrans_kernel(
    const _Float16* __restrict__ V, _Float16* __restrict__ Vt) {
  __shared__ _Float16 tb[64 * 72];
  const int bid = blockIdx.x;
  const int h = bid >> 7;
  const int lt = (bid >> 2) & 31;
  const int ft = bid & 3;
  const int l0 = lt << 6, f0 = ft << 6;
  const int t = threadIdx.x;
  const int r = t >> 2, s = (t & 3) << 4;
  const _Float16* src = V + (((size_t)h * 2048 + l0 + r) << 8) + f0 + s;
  *(f16x8*)(tb + r * 72 + s) = *(const f16x8*)src;
  *(f16x8*)(tb + r * 72 + s + 8) = *(const f16x8*)(src + 8);
  __syncthreads();
  _Float16 buf[16];
#pragma unroll
  for (int j = 0; j < 16; ++j) buf[j] = tb[(s + j) * 72 + r];
  _Float16* dst = Vt + (((size_t)(h << 8) + f0 + r) << 11) + l0 + s;
  *(f16x8*)dst = *(f16x8*)buf;
  *(f16x8*)(dst + 8) = *(f16x8*)(buf + 8);
}

// ---------------- Kernel B: flash attention, S^T dataflow, MFMA 16x16x32 --------
// R7 schedule EXACTLY (512 blocks x 4 waves, wave = 32 q (2 qh); Ks+Vs double-
// buffered, one stage call/iter, vmcnt(8), 2 barriers) with ONE change: Ps LDS
// P^T-exchange replaced by intra-wave shfl exchange (verified R9-R11). Removes
// the Ps write->lgkm->read roundtrip from the serial chain; LDS 73->64KB.
// Occupancy lesson (R8-R11): grid 512 caps at 2 blocks/CU; R10's 16 waves/CU
// did NOT beat R7 -> kernel is serial-chain-bound, not wave-latency-bound.
__global__ __launch_bounds__(256, 2) void attn_kernel(
    const _Float16* __restrict__ Q, const _Float16* __restrict__ K,
    const _Float16* __restrict__ Vt, _Float16* __restrict__ O) {
  __shared__ _Float16 Ks[2][32 * 256];     // swizzled: mem[row][u]=K[row][u^(row&7)]
  __shared__ _Float16 Vs[2][256 * 32];     // 16B slots XOR-swizzled: i' = i ^ (g&7)
  const int i = blockIdx.x;
  const int h = (i & 7) * 4 + (i >> 7);    // XCD-aware: 4 heads per XCD
  const int qt = (i >> 3) & 15;
  const int tid = threadIdx.x;
  const int w = tid >> 6, lane = tid & 63;
  const int l15 = lane & 15, quad = lane >> 4;
  const int q0 = qt * 128 + w * 32;

  const _Float16* Kt = K + (((size_t)h * 2048) << 8);
  const _Float16* Vtb = Vt + (((size_t)h << 8) << 11);

  // Q fragments as B-operand (n=query=l15, k=feat=kc*32+quad*8+j)
  f16x8 qf[2][8];
#pragma unroll
  for (int qh = 0; qh < 2; ++qh) {
    const _Float16* qb = Q + (((size_t)h * 2048 + q0 + qh * 16 + l15) << 8) + quad * 8;
#pragma unroll
    for (int kc = 0; kc < 8; ++kc) qf[qh][kc] = *(const f16x8*)(qb + kc * 32);
  }

  // O^T accumulators: oacc[qh][fb][r] = O^T[feat=fb*16+quad*4+r][query=qh*16+l15]
  f32x4 oacc[2][16];
#pragma unroll
  for (int qh = 0; qh < 2; ++qh)
#pragma unroll
    for (int fb = 0; fb < 16; ++fb) oacc[qh][fb] = (f32x4){0.f, 0.f, 0.f, 0.f};
  float m2[2] = {-1e30f, -1e30f};  // running max per query (base-2 units)
  float ell[2] = {0.f, 0.f};      // lane-partial (this quad's keys)
  const float SC = 23.083120654223414f;  // 16 * log2(e)

  auto stage_tile = [&](int kt, int bb) {
    const int k0 = kt * 32;
#pragma unroll
    for (int o = 0; o < 4; ++o) {
      const int c = tid + o * 256;
      const int row = c >> 5, unit = c & 31;
      stage16(Kt + (((size_t)(k0 + row)) << 8) + ((unit ^ (row & 7)) << 3),
              &Ks[bb][c * 8]);
      // Vs: physical 16B slot c; logical slot sl = (g<<3)|(ip^(g&7)) (involution)
      const int g = c >> 3, ip = c & 7;
      const int sl = (g << 3) | (ip ^ (g & 7));
      const int f = sl >> 2, ku = sl & 3;
      stage16(Vtb + (((size_t)f) << 11) + k0 + ku * 8, &Vs[bb][c * 8]);
    }
  };

  stage_tile(0, 0);
  for (int kt = 0; kt < 64; ++kt) {
    const int cb = kt & 1;
    if (kt < 63) {
      stage_tile(kt + 1, cb ^ 1);
      asm volatile("s_waitcnt vmcnt(8)" ::: "memory");
    } else {
      asm volatile("s_waitcnt vmcnt(0)" ::: "memory");
    }
    __builtin_amdgcn_s_barrier();
    asm volatile("" ::: "memory");

    // S^T = K Q^T : c[kh][qh]; D[m=key=quad*4+r][n=query=l15]
    f32x4 c00 = {0.f, 0.f, 0.f, 0.f}, c01 = c00, c10 = c00, c11 = c00;
#pragma unroll
    for (int kc = 0; kc < 8; ++kc) {
      const int u0 = ((kc * 4 + quad) ^ (l15 & 7)) << 3;
      f16x8 kf0 = *(const f16x8*)(&Ks[cb][l15 * 256 + u0]);
      f16x8 kf1 = *(const f16x8*)(&Ks[cb][(16 + l15) * 256 + u0]);
      c00 = __builtin_amdgcn_mfma_f32_16x16x32_f16(kf0, qf[0][kc], c00, 0, 0, 0);
      c01 = __builtin_amdgcn_mfma_f32_16x16x32_f16(kf0, qf[1][kc], c01, 0, 0, 0);
      c10 = __builtin_amdgcn_mfma_f32_16x16x32_f16(kf1, qf[0][kc], c10, 0, 0, 0);
      c11 = __builtin_amdgcn_mfma_f32_16x16x32_f16(kf1, qf[1][kc], c11, 0, 0, 0);
    }

    // online softmax: in-lane 8-max + xor16/xor32; defer-max threshold 8 (T13)
    float alpha[2];
    unsigned int pA0[2], pA1[2], pB0[2], pB1[2];  // pk2'd P^T quarters (kh0/kh1)
    bool upd = false;
#pragma unroll
    for (int qh = 0; qh < 2; ++qh) {
      const f32x4 ck0 = qh ? c01 : c00;
      const f32x4 ck1 = qh ? c11 : c10;
      float s0[4], s1[4];
#pragma unroll
      for (int r = 0; r < 4; ++r) { s0[r] = ck0[r] * SC; s1[r] = ck1[r] * SC; }
      float mx = fmaxf(fmaxf(fmaxf(s0[0], s0[1]), fmaxf(s0[2], s0[3])),
                       fmaxf(fmaxf(s1[0], s1[1]), fmaxf(s1[2], s1[3])));
      mx = fmaxf(mx, __shfl_xor(mx, 16));
      mx = fmaxf(mx, __shfl_xor(mx, 32));
      const float mo = m2[qh];
      const bool u8 = (mx > mo + 8.f);   // defer-max: P bounded by 2^8
      const float mn = u8 ? mx : mo;
      m2[qh] = mn;
      upd |= u8;
      const float a = exp2f(mo - mn);
      alpha[qh] = a;
      float p0[4], p1[4];
#pragma unroll
      for (int r = 0; r < 4; ++r) { p0[r] = exp2f(s0[r] - mn); p1[r] = exp2f(s1[r] - mn); }
      ell[qh] = ell[qh] * a + ((p0[0] + p0[1]) + (p0[2] + p0[3])) +
                ((p1[0] + p1[1]) + (p1[2] + p1[3]));
      pA0[qh] = pk2(p0[0], p0[1]);
      pA1[qh] = pk2(p0[2], p0[3]);
      pB0[qh] = pk2(p1[0], p1[1]);
      pB1[qh] = pk2(p1[2], p1[3]);
    }
    if (__any(upd)) {
#pragma unroll
      for (int qh = 0; qh < 2; ++qh)
#pragma unroll
        for (int fb = 0; fb < 16; ++fb) oacc[qh][fb] *= alpha[qh];
    }
    // P^T exchange intra-wave: target (quad,l15) needs row dwords 4*quad..4*quad+3
    // = {A0,A1}(srcLo,srcHi) for quad<2, {B0,B1}(srcLo,srcHi) for quad>=2,
    // srcLo = quad 2*(quad&1), srcHi = srcLo+1 (same l15).
    f16x8 pf[2];
    {
      const int srcLo = ((quad & 1) << 5) | l15;
      const int srcHi = srcLo + 16;
      const bool hi = (quad >> 1) != 0;
#pragma unroll
      for (int qh = 0; qh < 2; ++qh) {
        unsigned int a0 = __shfl(pA0[qh], srcLo), b0 = __shfl(pB0[qh], srcLo);
        unsigned int a1 = __shfl(pA1[qh], srcLo), b1 = __shfl(pB1[qh], srcLo);
        unsigned int a2 = __shfl(pA0[qh], srcHi), b2 = __shfl(pB0[qh], srcHi);
        unsigned int a3 = __shfl(pA1[qh], srcHi), b3 = __shfl(pB1[qh], srcHi);
        union { f16x8 v; unsigned int d[4]; } tp;
        tp.d[0] = hi ? b0 : a0;
        tp.d[1] = hi ? b1 : a1;
        tp.d[2] = hi ? b2 : a2;
        tp.d[3] = hi ? b3 : a3;
        pf[qh] = tp.v;
      }
    }
    // O^T += V^T P^T (vf shared across qh); Vs read via slot swizzle (conflict-free)
#pragma unroll
    for (int fb = 0; fb < 16; ++fb) {
      const int f = fb * 16 + l15;
      const int g = f >> 1;
      const int ip = (((f & 1) << 2) | quad) ^ (g & 7);
      f16x8 vf = *(const f16x8*)(&Vs[cb][(((g << 3) | ip)) * 8]);
      oacc[0][fb] = __builtin_amdgcn_mfma_f32_16x16x32_f16(vf, pf[0], oacc[0][fb], 0, 0, 0);
      oacc[1][fb] = __builtin_amdgcn_mfma_f32_16x16x32_f16(vf, pf[1], oacc[1][fb], 0, 0, 0);
    }
    asm volatile("" ::: "memory");
    __builtin_amdgcn_s_barrier();
  }

  // epilogue: reduce lane-partial ell over quads, write O[h][query][feat]
#pragma unroll
  for (int qh = 0; qh < 2; ++qh) {
    float e = ell[qh];
    e += __shfl_xor(e, 16);
    e += __shfl_xor(e, 32);
    const float inv = 1.f / e;
    _Float16* ob = O + (((size_t)h * 2048 + q0 + qh * 16 + l15) << 8) + quad * 4;
#pragma unroll
    for (int fb = 0; fb < 16; ++fb) {
      f16x4 ov;
#pragma unroll
      for (int r = 0; r < 4; ++r) ov[r] = (_Float16)(oacc[qh][fb][r] * inv);
      *(f16x4*)(ob + fb * 16) = ov;
    }
  }
}

// ---------------- Kernel C: gather + output bilinear via split-f16 MFMA ---------
// Reassociated: out = pu^T (os pv). gemm1: G[n][k] = sum_d os[n][d] pv[d][k]
// (os is exact f16 from O -> 2-term split). gemm2: out[m][k] = sum_n pu[n][m]
// G[n][k] (pu, G split -> 3-term). LDS 40KB (G planes reuse os/pvt regions).
__global__ __launch_bounds__(256) void proj_kernel(
    const _Float16* __restrict__ O, const float* __restrict__ pu,
    const float* __restrict__ pv, float* __restrict__ out) {
  __shared__ _Float16 sm[20480];   // 40 KB
  _Float16* os = sm;               // [n=64][d=64] swz (f16 exact)
  _Float16* put_hi = sm + 4096;    // [m=64][n=64] swz
  _Float16* put_lo = sm + 8192;
  _Float16* pvt_hi = sm + 12288;   // [k=64][d=64] swz
  _Float16* pvt_lo = sm + 16384;
  _Float16* gt_hi = sm;            // [k=64][n=64] swz, reuses os region
  _Float16* gt_lo = sm + 12288;    // reuses pvt_hi region
  const int bl = blockIdx.x;
  const int b = bl >> 11, l = bl & 2047;
  const int t = threadIdx.x;
  const int w = t >> 6, lane = t & 63;
  const int l15 = lane & 15, quad = lane >> 4;

  {  // gather this (b,l)'s 64x64 attention output -> os[n][d] f16 swizzled
    const int hh = t >> 4, hc = t & 15;
    const int mc = hh >> 2, mr = hh & 3;
    const int hg = (b << 4) | hh;
    const _Float16* src = O + (((size_t)hg * 2048 + l) << 8) + hc * 16;
    const int n = mc * 16 + hc, d0 = mr * 16;
    f16x8 v0 = *(const f16x8*)(src);
    f16x8 v1 = *(const f16x8*)(src + 8);
    *(f16x8*)(os + (n << 6) + ((((d0 >> 3) + 0) ^ (n & 7)) << 3)) = v0;
    *(f16x8*)(os + (n << 6) + ((((d0 >> 3) + 1) ^ (n & 7)) << 3)) = v1;
  }
  {  // stage pu -> put[m][n] hi/lo; pv -> pvt[k][d] hi/lo (strided scalar, L2-hot)
    const int c = t & 63, wq = t >> 6;
#pragma unroll
    for (int rr = 0; rr < 2; ++rr) {
      const int r0 = wq * 8 + rr * 32;
      f16x8 uh, ul, vh, vl;
#pragma unroll
      for (int j = 0; j < 8; ++j) {
        hl16 su = split_f16(pu[(r0 + j) * 64 + c]);
        hl16 sv = split_f16(pv[(r0 + j) * 64 + c]);
        uh[j] = su.h; ul[j] = su.l;
        vh[j] = sv.h; vl[j] = sv.l;
      }
      const int un = ((r0 >> 3) ^ (c & 7)) << 3;
      *(f16x8*)(put_hi + (c << 6) + un) = uh;
      *(f16x8*)(put_lo + (c << 6) + un) = ul;
      *(f16x8*)(pvt_hi + (c << 6) + un) = vh;
      *(f16x8*)(pvt_lo + (c << 6) + un) = vl;
    }
  }
  __syncthreads();

  // gemm1: G[n][k] = sum_d os[n][d] pv[d][k]; wave w owns k in [w*16, w*16+16)
  f32x4 gacc[4];
#pragma unroll
  for (int nt = 0; nt < 4; ++nt) gacc[nt] = (f32x4){0.f, 0.f, 0.f, 0.f};
  {
    const int k = (w << 4) | l15;
#pragma unroll
    for (int ks = 0; ks < 2; ++ks) {
      const int uk = (((ks * 4 + quad) ^ (k & 7)) << 3);
      f16x8 bh = *(const f16x8*)(pvt_hi + (k << 6) + uk);
      f16x8 blo = *(const f16x8*)(pvt_lo + (k << 6) + uk);
#pragma unroll
      for (int nt = 0; nt < 4; ++nt) {
        const int n = (nt << 4) | l15;
        const int un = (((ks * 4 + quad) ^ (n & 7)) << 3);
        f16x8 a = *(const f16x8*)(os + (n << 6) + un);
        gacc[nt] = __builtin_amdgcn_mfma_f32_16x16x32_f16(a, bh, gacc[nt], 0, 0, 0);
        gacc[nt] = __builtin_amdgcn_mfma_f32_16x16x32_f16(a, blo, gacc[nt], 0, 0, 0);
      }
    }
  }
  __syncthreads();  // all waves done reading os/pvt before G overwrites them
  {
    const int k = (w << 4) | l15;
#pragma unroll
    for (int nt = 0; nt < 4; ++nt) {
#pragma unroll
      for (int r = 0; r < 4; ++r) {
        const int n = (nt << 4) | (quad << 2) | r;
        const int off = (k << 6) + ((((n >> 3) ^ (k & 7)) << 3) | (n & 7));
        hl16 sg = split_f16(gacc[nt][r]);
        gt_hi[off] = sg.h;
        gt_lo[off] = sg.l;
      }
    }
  }
  __syncthreads();

  // gemm2: out[m][k] = sum_n pu[n][m] G[n][k]; wave w owns k in [w*16, w*16+16)
  {
    f32x4 cacc[4];
#pragma unroll
    for (int mt = 0; mt < 4; ++mt) cacc[mt] = (f32x4){0.f, 0.f, 0.f, 0.f};
    const int k = (w << 4) | l15;
#pragma unroll
    for (int ks = 0; ks < 2; ++ks) {
      const int uk = (((ks * 4 + quad) ^ (k & 7)) << 3);
      f16x8 bh = *(const f16x8*)(gt_hi + (k << 6) + uk);
      f16x8 blo = *(const f16x8*)(gt_lo + (k << 6) + uk);
#pragma unroll
      for (int mt = 0; mt < 4; ++mt) {
        const int m = (mt << 4) | l15;
        const int um = (((ks * 4 + quad) ^ (m & 7)) << 3);
        f16x8 ah = *(const f16x8*)(put_hi + (m << 6) + um);
        f16x8 al = *(const f16x8*)(put_lo + (m << 6) + um);
        cacc[mt] = __builtin_amdgcn_mfma_f32_16x16x32_f16(ah, bh, cacc[mt], 0, 0, 0);
        cacc[mt] = __builtin_amdgcn_mfma_f32_16x16x32_f16(ah, blo, cacc[mt], 0, 0, 0);
        cacc[mt] = __builtin_amdgcn_mfma_f32_16x16x32_f16(al, bh, cacc[mt], 0, 0, 0);
      }
    }
    float* og = out + ((size_t)bl << 12);
#pragma unroll
    for (int mt = 0; mt < 4; ++mt) {
#pragma unroll
      for (int r = 0; r < 4; ++r) {
        const int m = (mt << 4) | (quad << 2) | r;
        og[m * 64 + k] = cacc[mt][r];
      }
    }
  }
}

extern "C" void kernel_launch(void* const* d_in, const int* in_sizes, int n_in,
                              void* d_out, int out_size, void* d_ws, size_t ws_size,
                              hipStream_t stream) {
  (void)in_sizes; (void)n_in; (void)out_size; (void)ws_size;
  const float* x = (const float*)d_in[0];
  const float* u = (const float*)d_in[1];
  const float* v = (const float*)d_in[2];
  const float* pu = (const float*)d_in[3];
  const float* pv = (const float*)d_in[4];
  const size_t SEG = (size_t)32 * 2048 * 256;  // 16.7M f16 elements
  _Float16* Q = (_Float16*)d_ws;
  _Float16* K = Q + SEG;
  _Float16* Vt = K + SEG;
  _Float16* O = Vt + SEG;  // also V staging (consumed by vtrans before O writes)
  _Float16* V = O;
  qkv_kernel<<<4096, 256, 0, stream>>>(x, u, v, Q, K, V);
  vtrans_kernel<<<4096, 256, 0, stream>>>(V, Vt);
  attn_kernel<<<512, 256, 0, stream>>>(Q, K, Vt, O);
  proj_kernel<<<4096, 256, 0, stream>>>(O, pu, pv, (float*)d_out);
}